// Round 1
// baseline (519.023 us; speedup 1.0000x reference)
//
#include <hip/hip_runtime.h>
#include <math.h>

namespace {

constexpr int Nn  = 2;
constexpr int Cc  = 512;
constexpr int Dd  = 32;
constexpr int HW  = 196;
constexpr int HWP = 224;            // padded HW (zeros), 224 = 16*14
constexpr int OC  = 2048;           // NUM_OUTS * C
constexpr int CK  = 16;             // c-chunk for LDS staging
constexpr float TEMP   = 0.35355339059327373f;  // 1/sqrt(KEY_DIM)
constexpr float INV196 = 1.0f / 196.0f;

// ---------------- transpose (generic, 64x64 tiles) ----------------
__global__ void transpose_k(const float* __restrict__ src, float* __restrict__ dst,
                            int R, int Ccol) {
  __shared__ float tile[64][65];
  int nbc = (Ccol + 63) >> 6;
  int br = blockIdx.x / nbc, bc = blockIdx.x - br * nbc;
  int r0 = br << 6, c0 = bc << 6;
  int lc = threadIdx.x & 63, lr = threadIdx.x >> 6;
  for (int rr = lr; rr < 64; rr += 4) {
    int r = r0 + rr, c = c0 + lc;
    tile[rr][lc] = (r < R && c < Ccol) ? src[(size_t)r * Ccol + c] : 0.f;
  }
  __syncthreads();
  for (int rr = lr; rr < 64; rr += 4) {
    int c = c0 + rr, r = r0 + lc;
    if (c < Ccol && r < R) dst[(size_t)c * R + r] = tile[lc][rr];
  }
}

// ---------------- avgpool 3x3 + spatial mean ----------------
// grid: N*C*D blocks (b = (n*C + c)*D + d), 256 threads (one per h,w)
__global__ void pool_kernel(const float* __restrict__ x, float* __restrict__ xp,
                            float* __restrict__ xm) {
  int b = blockIdx.x;
  int d = b & 31;
  int rem = b >> 5;
  int c = rem & 511;
  int n = rem >> 9;
  int t = threadIdx.x;
  __shared__ float tl[256];
  __shared__ float red[4];
  float v = x[(size_t)b * 256 + t];
  tl[t] = v;
  float s = v;
  #pragma unroll
  for (int off = 32; off; off >>= 1) s += __shfl_down(s, off, 64);
  if ((t & 63) == 0) red[t >> 6] = s;
  __syncthreads();
  size_t base = ((size_t)(n * Dd + d) * Cc + c) * HWP;
  if (t < HW) {
    int y = t / 14;
    int xx = t - y * 14;
    const float* p = &tl[y * 16 + xx];
    float s9 = p[0] + p[1] + p[2] + p[16] + p[17] + p[18] + p[32] + p[33] + p[34];
    xp[base + t] = s9 * (1.0f / 9.0f);
  } else if (t < HWP) {
    xp[base + t] = 0.0f;                     // zero pad -> contributes 0 to moments/s
  }
  if (t == 0) xm[(n * Dd + d) * Cc + c] = (red[0] + red[1] + red[2] + red[3]) * (1.0f / 256.0f);
}

// ---------------- query = Wq @ xm  (per (n,d)) ----------------
__global__ void query_kernel(const float* __restrict__ Wq, const float* __restrict__ xm,
                             float* __restrict__ qb) {
  int nd = blockIdx.x;
  int t = threadIdx.x;
  __shared__ float xs[512];
  xs[t] = xm[nd * Cc + t];
  xs[t + 256] = xm[nd * Cc + t + 256];
  __syncthreads();
  int k = t >> 3, j = t & 7;
  float p = 0.f;
  #pragma unroll 8
  for (int c = j; c < Cc; c += 8) p = fmaf(Wq[k * Cc + c], xs[c], p);
  p += __shfl_xor(p, 4, 8);
  p += __shfl_xor(p, 2, 8);
  p += __shfl_xor(p, 1, 8);
  if (j == 0) qb[nd * 32 + k] = p;
}

// ---------------- k-GEMM + softmax + s = xp @ attn   (per (n,d,o)) ----------------
__global__ void attn_kernel(const float* __restrict__ WkT, const float* __restrict__ xp,
                            const float* __restrict__ qb, float* __restrict__ attn_out,
                            float* __restrict__ sbuf) {
  int b = blockIdx.x;
  int o = b & 3, nd = b >> 2;
  int t = threadIdx.x;
  __shared__ float xt[CK][HWP];
  __shared__ float wk[CK][8];
  __shared__ float attn_l[HWP];
  __shared__ float red[4];
  __shared__ float qs[8];
  if (t < 8) qs[t] = qb[nd * 32 + o * 8 + t];
  float acc[8] = {0.f, 0.f, 0.f, 0.f, 0.f, 0.f, 0.f, 0.f};
  const float* xpnd = xp + (size_t)nd * Cc * HWP;
  for (int c0 = 0; c0 < Cc; c0 += CK) {
    __syncthreads();
    if (t < HWP) {
      #pragma unroll
      for (int r = 0; r < CK; ++r) xt[r][t] = xpnd[(size_t)(c0 + r) * HWP + t];
    }
    if (t < CK * 8) {
      int cc = t >> 3, kd = t & 7;
      wk[cc][kd] = WkT[(c0 + cc) * 32 + o * 8 + kd];
    }
    __syncthreads();
    if (t < HW) {
      #pragma unroll
      for (int cc = 0; cc < CK; ++cc) {
        float xv = xt[cc][t];
        float4 w0 = *(const float4*)&wk[cc][0];
        float4 w1 = *(const float4*)&wk[cc][4];
        acc[0] = fmaf(w0.x, xv, acc[0]); acc[1] = fmaf(w0.y, xv, acc[1]);
        acc[2] = fmaf(w0.z, xv, acc[2]); acc[3] = fmaf(w0.w, xv, acc[3]);
        acc[4] = fmaf(w1.x, xv, acc[4]); acc[5] = fmaf(w1.y, xv, acc[5]);
        acc[6] = fmaf(w1.z, xv, acc[6]); acc[7] = fmaf(w1.w, xv, acc[7]);
      }
    }
  }
  float dot = 0.f;
  if (t < HW) {
    #pragma unroll
    for (int kd = 0; kd < 8; ++kd) dot = fmaf(qs[kd], acc[kd], dot);
    dot *= TEMP;
  }
  float dval = (t < HW) ? dot : -3.0e38f;
  float m = dval;
  #pragma unroll
  for (int off = 32; off; off >>= 1) m = fmaxf(m, __shfl_xor(m, off, 64));
  __syncthreads();
  if ((t & 63) == 0) red[t >> 6] = m;
  __syncthreads();
  float bm = fmaxf(fmaxf(red[0], red[1]), fmaxf(red[2], red[3]));
  float e = (t < HW) ? expf(dval - bm) : 0.f;
  float se = e;
  #pragma unroll
  for (int off = 32; off; off >>= 1) se += __shfl_xor(se, off, 64);
  __syncthreads();
  if ((t & 63) == 0) red[t >> 6] = se;
  __syncthreads();
  float bs = red[0] + red[1] + red[2] + red[3];
  float attn = e / bs;                         // 0 for pad lanes (e == 0)
  if (t < HWP) attn_l[t] = attn;
  if (t < HW) {
    int n = nd >> 5, d = nd & 31;
    attn_out[(((size_t)n * 4 + o) * 32 + d) * HW + t] = attn;
  }
  // phase B: s[c] = sum_hw attn[hw] * xp[c][hw]
  for (int c0 = 0; c0 < Cc; c0 += CK) {
    __syncthreads();
    if (t < HWP) {
      #pragma unroll
      for (int r = 0; r < CK; ++r) xt[r][t] = xpnd[(size_t)(c0 + r) * HWP + t];
    }
    __syncthreads();
    int cl = t >> 4, g = t & 15;
    float p = 0.f;
    #pragma unroll
    for (int i = 0; i < HWP / 16; ++i) {
      int hw = g + 16 * i;
      p = fmaf(attn_l[hw], xt[cl][hw], p);
    }
    p += __shfl_xor(p, 8, 16);
    p += __shfl_xor(p, 4, 16);
    p += __shfl_xor(p, 2, 16);
    p += __shfl_xor(p, 1, 16);
    if (g == 0) sbuf[((size_t)nd * 4 + o) * Cc + c0 + cl] = p;
  }
}

// ---------------- the big one: per-(n,d,oc) moments of v = Wv @ xp ----------------
// grid: ND * 32 blocks; block tile = 64 oc x 224 hw, thread = 4 oc x 14 hw
__global__ __launch_bounds__(256) void moments_kernel(const float* __restrict__ WvT,
                                                      const float* __restrict__ xp,
                                                      float* __restrict__ S1,
                                                      float* __restrict__ S2) {
  int b = blockIdx.x;
  int og = b & 31, nd = b >> 5;
  int t = threadIdx.x;
  int ogl = t >> 4, hg = t & 15;
  __shared__ float xt[CK][HWP];
  __shared__ float wv[CK][64];
  float acc[4][14];
  #pragma unroll
  for (int a = 0; a < 4; ++a)
    #pragma unroll
    for (int j = 0; j < 14; ++j) acc[a][j] = 0.f;
  const float* xpnd = xp + (size_t)nd * Cc * HWP;
  const int ocb = og << 6;
  for (int c0 = 0; c0 < Cc; c0 += CK) {
    __syncthreads();
    if (t < HWP) {
      #pragma unroll
      for (int r = 0; r < CK; ++r) xt[r][t] = xpnd[(size_t)(c0 + r) * HWP + t];
    }
    {
      int ccb = t >> 6, ol = t & 63;
      #pragma unroll
      for (int i = 0; i < CK / 4; ++i)
        wv[ccb + 4 * i][ol] = WvT[(size_t)(c0 + ccb + 4 * i) * OC + ocb + ol];
    }
    __syncthreads();
    #pragma unroll
    for (int cc = 0; cc < CK; ++cc) {
      float4 a4 = *(const float4*)&wv[cc][ogl << 2];
      float xv[14];
      #pragma unroll
      for (int j = 0; j < 7; ++j) {
        float2 x2 = *(const float2*)&xt[cc][hg * 14 + 2 * j];
        xv[2 * j] = x2.x;
        xv[2 * j + 1] = x2.y;
      }
      #pragma unroll
      for (int j = 0; j < 14; ++j) {
        acc[0][j] = fmaf(a4.x, xv[j], acc[0][j]);
        acc[1][j] = fmaf(a4.y, xv[j], acc[1][j]);
        acc[2][j] = fmaf(a4.z, xv[j], acc[2][j]);
        acc[3][j] = fmaf(a4.w, xv[j], acc[3][j]);
      }
    }
  }
  float s1[4], s2[4];
  #pragma unroll
  for (int a = 0; a < 4; ++a) {
    float u = 0.f, w = 0.f;
    #pragma unroll
    for (int j = 0; j < 14; ++j) { u += acc[a][j]; w = fmaf(acc[a][j], acc[a][j], w); }
    s1[a] = u; s2[a] = w;
  }
  #pragma unroll
  for (int off = 8; off; off >>= 1) {
    #pragma unroll
    for (int a = 0; a < 4; ++a) {
      s1[a] += __shfl_xor(s1[a], off, 16);
      s2[a] += __shfl_xor(s2[a], off, 16);
    }
  }
  if (hg == 0) {
    size_t o0 = (size_t)nd * OC + ocb + (ogl << 2);
    #pragma unroll
    for (int a = 0; a < 4; ++a) { S1[o0 + a] = s1[a]; S2[o0 + a] = s2[a]; }
  }
}

// ---------------- epilogue: norm-fused attention output + gelu + head ----------------
// per (n,d,o): dotW[c] = Wv[o*512+c] . s ; out = gelu(gamma*rs*(dotW-mu)+beta); reduce w/ Wout
__global__ void head_kernel(const float* __restrict__ WvT, const float* __restrict__ sbuf,
                            const float* __restrict__ S1, const float* __restrict__ S2,
                            const float* __restrict__ gamma, const float* __restrict__ beta,
                            const float* __restrict__ Wout, const float* __restrict__ bout,
                            float* __restrict__ outs) {
  int b = blockIdx.x;
  int o = b & 3, nd = b >> 2;
  int t = threadIdx.x;
  __shared__ float ss[512];
  __shared__ float red[4];
  ss[t] = sbuf[((size_t)nd * 4 + o) * Cc + t];
  ss[t + 256] = sbuf[((size_t)nd * 4 + o) * Cc + t + 256];
  __syncthreads();
  float d0 = 0.f, d1 = 0.f;
  #pragma unroll 8
  for (int cp = 0; cp < Cc; ++cp) {
    const float* rowp = WvT + (size_t)cp * OC + o * Cc;
    float sv = ss[cp];
    d0 = fmaf(rowp[t], sv, d0);
    d1 = fmaf(rowp[t + 256], sv, d1);
  }
  float partial = 0.f;
  #pragma unroll
  for (int i = 0; i < 2; ++i) {
    int c = t + (i << 8);
    int oc = o * Cc + c;
    float m1 = S1[(size_t)nd * OC + oc] * INV196;
    float m2 = S2[(size_t)nd * OC + oc] * INV196;
    float var = m2 - m1 * m1;
    float rs = rsqrtf(var + 1e-5f);
    float dv = (i == 0) ? d0 : d1;
    float xh = (dv - m1) * rs * gamma[oc] + beta[oc];
    float ge = 0.5f * xh * (1.0f + erff(xh * 0.70710678118654752f));
    partial = fmaf(ge, Wout[o * Cc + c], partial);
  }
  float s = partial;
  #pragma unroll
  for (int off = 32; off; off >>= 1) s += __shfl_down(s, off, 64);
  if ((t & 63) == 0) red[t >> 6] = s;
  __syncthreads();
  if (t == 0) {
    int n = nd >> 5, d = nd & 31;
    outs[o * 64 + n * 32 + d] = red[0] + red[1] + red[2] + red[3] + bout[o];
  }
}

}  // namespace

extern "C" void kernel_launch(void* const* d_in, const int* in_sizes, int n_in,
                              void* d_out, int out_size, void* d_ws, size_t ws_size,
                              hipStream_t stream) {
  const float* x     = (const float*)d_in[0];
  const float* Wq    = (const float*)d_in[1];
  const float* Wk    = (const float*)d_in[2];
  const float* Wv    = (const float*)d_in[3];
  const float* gamma = (const float*)d_in[4];
  const float* beta  = (const float*)d_in[5];
  const float* Wout  = (const float*)d_in[6];
  const float* bout  = (const float*)d_in[7];
  float* out      = (float*)d_out;
  float* attn_out = out;            // (N,4,D,196) = 50176 floats
  float* outs     = out + 50176;    // (4,N,1,D)   = 256 floats

  float* ws  = (float*)d_ws;
  float* WvT = ws;                  // 512*2048      = 1048576
  float* WkT = WvT + 1048576;       // 512*32        = 16384
  float* xp  = WkT + 16384;         // 64*512*224    = 7340032
  float* xm  = xp + 7340032;        // 64*512        = 32768
  float* qb  = xm + 32768;          // 64*32         = 2048
  float* sb  = qb + 2048;           // 64*4*512      = 131072
  float* S1  = sb + 131072;         // 64*2048       = 131072
  float* S2  = S1 + 131072;         // 64*2048       = 131072

  transpose_k<<<256, 256, 0, stream>>>(Wv, WvT, 2048, 512);   // 32*8 tiles
  transpose_k<<<8, 256, 0, stream>>>(Wk, WkT, 32, 512);       // 1*8 tiles
  pool_kernel<<<Nn * Cc * Dd, 256, 0, stream>>>(x, xp, xm);
  query_kernel<<<Nn * Dd, 256, 0, stream>>>(Wq, xm, qb);
  attn_kernel<<<Nn * Dd * 4, 256, 0, stream>>>(WkT, xp, qb, attn_out, sb);
  moments_kernel<<<Nn * Dd * 32, 256, 0, stream>>>(WvT, xp, S1, S2);
  head_kernel<<<Nn * Dd * 4, 256, 0, stream>>>(WvT, sb, S1, S2, gamma, beta, Wout, bout, outs);
}

// Round 2
// 251.185 us; speedup vs baseline: 2.0663x; 2.0663x over previous
//
#include <hip/hip_runtime.h>
#include <math.h>

namespace {

constexpr int Cc  = 512;
constexpr int HW  = 196;
constexpr int HWP = 224;
constexpr int OC  = 2048;
constexpr float TEMP   = 0.35355339059327373f;  // 1/sqrt(KEY_DIM)
constexpr float INV196 = 1.0f / 196.0f;

typedef __attribute__((ext_vector_type(8))) short short8;
typedef __attribute__((ext_vector_type(4))) float f32x4;

__device__ __forceinline__ unsigned short f2bf(float x) {
  union { float f; unsigned int u; } v; v.f = x;
  unsigned int r = v.u + 0x7FFFu + ((v.u >> 16) & 1u);
  return (unsigned short)(r >> 16);
}
__device__ __forceinline__ float bf2f(unsigned short b) {
  union { unsigned int u; float f; } v; v.u = ((unsigned int)b) << 16;
  return v.f;
}

#define MFMA16(a, b, c) __builtin_amdgcn_mfma_f32_16x16x32_bf16((a), (b), (c), 0, 0, 0)

// ---------------- transpose (generic, 64x64 tiles) — builds WvT for head ----------------
__global__ void transpose_k(const float* __restrict__ src, float* __restrict__ dst,
                            int R, int Ccol) {
  __shared__ float tile[64][65];
  int nbc = (Ccol + 63) >> 6;
  int br = blockIdx.x / nbc, bc = blockIdx.x - br * nbc;
  int r0 = br << 6, c0 = bc << 6;
  int lc = threadIdx.x & 63, lr = threadIdx.x >> 6;
  for (int rr = lr; rr < 64; rr += 4) {
    int r = r0 + rr, c = c0 + lc;
    tile[rr][lc] = (r < R && c < Ccol) ? src[(size_t)r * Ccol + c] : 0.f;
  }
  __syncthreads();
  for (int rr = lr; rr < 64; rr += 4) {
    int c = c0 + rr, r = r0 + lc;
    if (c < Ccol && r < R) dst[(size_t)c * R + r] = tile[lc][rr];
  }
}

// ---------------- Wv -> bf16 hi/lo A-fragment layout ----------------
// WvA[kk(16)][hl(2)][r(128)][lane(64)][e(8)] ; oc = r*16+(lane&15), c = kk*32+(lane>>4)*8+e
__global__ void convert_wv(const float* __restrict__ Wv, short* __restrict__ WvA) {
  int bid = blockIdx.x;               // 512
  int t = threadIdx.x;
  int kk = bid >> 5;
  int r = ((bid & 31) << 2) + (t >> 6);
  int lane = t & 63;
  int oc = r * 16 + (lane & 15);
  int c0 = kk * 32 + (lane >> 4) * 8;
  const float* src = Wv + (size_t)oc * 512 + c0;
  float4 v0 = *(const float4*)src;
  float4 v1 = *(const float4*)(src + 4);
  float vals[8] = {v0.x, v0.y, v0.z, v0.w, v1.x, v1.y, v1.z, v1.w};
  short8 hi, lo;
  #pragma unroll
  for (int e = 0; e < 8; ++e) {
    unsigned short h = f2bf(vals[e]);
    float rem = vals[e] - bf2f(h);
    hi[e] = (short)h;
    lo[e] = (short)f2bf(rem);
  }
  *(short8*)(WvA + ((size_t)(kk * 2 + 0) * 128 + r) * 512 + lane * 8) = hi;
  *(short8*)(WvA + ((size_t)(kk * 2 + 1) * 128 + r) * 512 + lane * 8) = lo;
}

// ---------------- avgpool 3x3 + spatial mean -> bf16 hi/lo xp in [nd][hw][c] ----------------
// grid: 64 nd * 64 cg blocks, 256 threads
__global__ void pool_kernel(const float* __restrict__ x, short* __restrict__ xpPH,
                            short* __restrict__ xpPL, float* __restrict__ xm) {
  int b = blockIdx.x;
  int cg = b & 63, nd = b >> 6;
  int n = nd >> 5, d = nd & 31;
  int c0 = cg * 8;
  int t = threadIdx.x;
  __shared__ float tl[8][264];
  int cl = t >> 5, s = t & 31;
  const float* xr = x + (((size_t)(n * 512 + c0 + cl)) * 32 + d) * 256;
  float4 va = *(const float4*)(xr + s * 8);
  float4 vb = *(const float4*)(xr + s * 8 + 4);
  *(float4*)&tl[cl][s * 8] = va;
  *(float4*)&tl[cl][s * 8 + 4] = vb;
  float rs = va.x + va.y + va.z + va.w + vb.x + vb.y + vb.z + vb.w;
  #pragma unroll
  for (int off = 16; off; off >>= 1) rs += __shfl_xor(rs, off, 32);
  if (s == 0) xm[nd * 512 + c0 + cl] = rs * (1.0f / 256.0f);
  __syncthreads();
  int c = t & 7, hwb = t >> 3;
  #pragma unroll
  for (int p = 0; p < 7; ++p) {
    int hw = p * 32 + hwb;
    float val = 0.f;
    if (hw < HW) {
      int y = hw / 14, xx = hw - y * 14;
      const float* q = &tl[c][y * 16 + xx];
      val = (q[0] + q[1] + q[2] + q[16] + q[17] + q[18] + q[32] + q[33] + q[34]) * (1.0f / 9.0f);
    }
    unsigned short h = f2bf(val);
    float rem = val - bf2f(h);
    size_t off = ((size_t)nd * HWP + hw) * 512 + c0 + c;
    xpPH[off] = (short)h;
    xpPL[off] = (short)f2bf(rem);
  }
}

// ---------------- query = Wq @ xm  (per (n,d)) ----------------
__global__ void query_kernel(const float* __restrict__ Wq, const float* __restrict__ xm,
                             float* __restrict__ qb) {
  int nd = blockIdx.x;
  int t = threadIdx.x;
  __shared__ float xs[512];
  xs[t] = xm[nd * Cc + t];
  xs[t + 256] = xm[nd * Cc + t + 256];
  __syncthreads();
  int k = t >> 3, j = t & 7;
  float p = 0.f;
  #pragma unroll 8
  for (int c = j; c < Cc; c += 8) p = fmaf(Wq[k * Cc + c], xs[c], p);
  p += __shfl_xor(p, 4, 8);
  p += __shfl_xor(p, 2, 8);
  p += __shfl_xor(p, 1, 8);
  if (j == 0) qb[nd * 32 + k] = p;
}

// ---------------- attention: qw=q^T Wk, dot per pixel, softmax, s = xp@attn (per nd) ----------------
__global__ __launch_bounds__(256) void attn_kernel(
    const float* __restrict__ Wk, const float* __restrict__ qb,
    const short* __restrict__ xpPH, const short* __restrict__ xpPL,
    float* __restrict__ attn_out, float* __restrict__ sbuf) {
  int nd = blockIdx.x;
  int t = threadIdx.x;
  __shared__ float qw[4][512];
  __shared__ float dot_l[4][256];
  __shared__ float attn_l[4][224];
  {
    int o = t >> 6;
    int c0 = (t & 63) * 8;
    float q[8];
    #pragma unroll
    for (int kd = 0; kd < 8; ++kd) q[kd] = qb[nd * 32 + o * 8 + kd];
    #pragma unroll
    for (int e = 0; e < 8; ++e) {
      float a = 0.f;
      #pragma unroll
      for (int kd = 0; kd < 8; ++kd) a = fmaf(q[kd], Wk[(size_t)(o * 8 + kd) * 512 + c0 + e], a);
      qw[o][c0 + e] = a;
    }
  }
  __syncthreads();
  float dot0 = 0.f, dot1 = 0.f, dot2 = 0.f, dot3 = 0.f;
  if (t < HWP) {
    const short8* rh = (const short8*)(xpPH + ((size_t)nd * HWP + t) * 512);
    const short8* rl = (const short8*)(xpPL + ((size_t)nd * HWP + t) * 512);
    for (int cb = 0; cb < 64; ++cb) {
      short8 h = rh[cb], l = rl[cb];
      #pragma unroll
      for (int e = 0; e < 8; ++e) {
        float xv = bf2f((unsigned short)h[e]) + bf2f((unsigned short)l[e]);
        dot0 = fmaf(qw[0][cb * 8 + e], xv, dot0);
        dot1 = fmaf(qw[1][cb * 8 + e], xv, dot1);
        dot2 = fmaf(qw[2][cb * 8 + e], xv, dot2);
        dot3 = fmaf(qw[3][cb * 8 + e], xv, dot3);
      }
    }
  }
  if (t < HW) {
    dot_l[0][t] = dot0 * TEMP;
    dot_l[1][t] = dot1 * TEMP;
    dot_l[2][t] = dot2 * TEMP;
    dot_l[3][t] = dot3 * TEMP;
  } else {
    #pragma unroll
    for (int o = 0; o < 4; ++o) dot_l[o][t] = -3.0e38f;
  }
  __syncthreads();
  {
    int o = t >> 6, l = t & 63;
    float v0 = dot_l[o][l], v1 = dot_l[o][l + 64], v2 = dot_l[o][l + 128], v3 = dot_l[o][l + 192];
    float m = fmaxf(fmaxf(v0, v1), fmaxf(v2, v3));
    #pragma unroll
    for (int off = 32; off; off >>= 1) m = fmaxf(m, __shfl_xor(m, off, 64));
    float e0 = expf(v0 - m), e1 = expf(v1 - m), e2 = expf(v2 - m), e3 = expf(v3 - m);
    float s = e0 + e1 + e2 + e3;
    #pragma unroll
    for (int off = 32; off; off >>= 1) s += __shfl_xor(s, off, 64);
    float inv = 1.0f / s;
    attn_l[o][l] = e0 * inv;
    attn_l[o][l + 64] = e1 * inv;
    attn_l[o][l + 128] = e2 * inv;
    if (l < 32) attn_l[o][l + 192] = e3 * inv;
    int n = nd >> 5, d = nd & 31;
    float* ao = attn_out + (((size_t)n * 4 + o) * 32 + d) * HW;
    ao[l] = e0 * inv;
    ao[l + 64] = e1 * inv;
    if (l + 128 < HW) ao[l + 128] = e2 * inv;
    if (l + 192 < HW) ao[l + 192] = e3 * inv;
  }
  __syncthreads();
  // phase B: s[o][c] = sum_hw attn[o][hw] * xp[hw][c]
  float sacc[4][2] = {{0.f,0.f},{0.f,0.f},{0.f,0.f},{0.f,0.f}};
  const short* ph = xpPH + (size_t)nd * HWP * 512;
  const short* pl = xpPL + (size_t)nd * HWP * 512;
  for (int hw = 0; hw < HW; ++hw) {
    float x0 = bf2f((unsigned short)ph[hw * 512 + t]) + bf2f((unsigned short)pl[hw * 512 + t]);
    float x1 = bf2f((unsigned short)ph[hw * 512 + t + 256]) + bf2f((unsigned short)pl[hw * 512 + t + 256]);
    #pragma unroll
    for (int o = 0; o < 4; ++o) {
      float a = attn_l[o][hw];
      sacc[o][0] = fmaf(a, x0, sacc[o][0]);
      sacc[o][1] = fmaf(a, x1, sacc[o][1]);
    }
  }
  #pragma unroll
  for (int o = 0; o < 4; ++o) {
    sbuf[((size_t)nd * 4 + o) * 512 + t] = sacc[o][0];
    sbuf[((size_t)nd * 4 + o) * 512 + t + 256] = sacc[o][1];
  }
}

// ---------------- moments via split-bf16 MFMA: per-(nd,oc) S1,S2 of v = Wv @ xp ----------------
// grid 2048 blocks (XCD-affine: all 32 ob-blocks of one nd on same XCD), 256 threads (4 waves)
// block tile 64 oc x 224 hw; wave w owns oc-frag w (16 oc) x 14 hw-frags
__global__ __launch_bounds__(256, 3) void moments_mfma(
    const short* __restrict__ WvA, const short* __restrict__ xpPH,
    const short* __restrict__ xpPL, float* __restrict__ S1, float* __restrict__ S2) {
  int bid = blockIdx.x;
  int ob = (bid >> 3) & 31;
  int nd = ((bid >> 8) << 3) | (bid & 7);
  int t = threadIdx.x;
  int w = t >> 6, lane = t & 63;
  __shared__ short lds[18432];   // A hi [0,2048) lo [2048,4096) ; B hi [4096,11264) lo [11264,18432)
  f32x4 acc[14];
  #pragma unroll
  for (int j = 0; j < 14; ++j) acc[j] = (f32x4){0.f, 0.f, 0.f, 0.f};

  const size_t xbase = (size_t)nd * HWP * 512;
  for (int kk = 0; kk < 16; ++kk) {
    __syncthreads();
    {
      const short* gh = WvA + ((size_t)(kk * 2 + 0) * 128 + (ob << 2)) * 512;
      const short* gl = WvA + ((size_t)(kk * 2 + 1) * 128 + (ob << 2)) * 512;
      short8 a0 = *(const short8*)(gh + t * 8);
      short8 a1 = *(const short8*)(gl + t * 8);
      if (t < HWP) {
        const short* bh = xpPH + xbase + (size_t)t * 512 + kk * 32;
        const short* bl = xpPL + xbase + (size_t)t * 512 + kk * 32;
        short8 b0 = ((const short8*)bh)[0], b1 = ((const short8*)bh)[1];
        short8 b2 = ((const short8*)bh)[2], b3 = ((const short8*)bh)[3];
        short8 c0 = ((const short8*)bl)[0], c1 = ((const short8*)bl)[1];
        short8 c2 = ((const short8*)bl)[2], c3 = ((const short8*)bl)[3];
        int hb = 4096 + (t >> 4) * 512 + (t & 15) * 8;
        *(short8*)(lds + hb)       = b0;
        *(short8*)(lds + hb + 128) = b1;
        *(short8*)(lds + hb + 256) = b2;
        *(short8*)(lds + hb + 384) = b3;
        int lb = hb + 7168;
        *(short8*)(lds + lb)       = c0;
        *(short8*)(lds + lb + 128) = c1;
        *(short8*)(lds + lb + 256) = c2;
        *(short8*)(lds + lb + 384) = c3;
      }
      *(short8*)(lds + t * 8) = a0;
      *(short8*)(lds + 2048 + t * 8) = a1;
    }
    __syncthreads();
    short8 ah = *(short8*)(lds + w * 512 + lane * 8);
    short8 al = *(short8*)(lds + 2048 + w * 512 + lane * 8);
    #pragma unroll
    for (int j = 0; j < 14; ++j) {
      short8 bh = *(short8*)(lds + 4096 + j * 512 + lane * 8);
      short8 bl = *(short8*)(lds + 11264 + j * 512 + lane * 8);
      acc[j] = MFMA16(ah, bh, acc[j]);
      acc[j] = MFMA16(al, bh, acc[j]);
      acc[j] = MFMA16(ah, bl, acc[j]);
    }
  }
  // epilogue: S1 = sum_hw v, S2 = sum_hw v^2 (pad hw cols are exactly 0)
  float p1[4] = {0.f, 0.f, 0.f, 0.f}, p2[4] = {0.f, 0.f, 0.f, 0.f};
  #pragma unroll
  for (int j = 0; j < 14; ++j)
    #pragma unroll
    for (int r = 0; r < 4; ++r) {
      float v = acc[j][r];
      p1[r] += v;
      p2[r] = fmaf(v, v, p2[r]);
    }
  #pragma unroll
  for (int off = 8; off; off >>= 1)
    #pragma unroll
    for (int r = 0; r < 4; ++r) {
      p1[r] += __shfl_xor(p1[r], off, 16);
      p2[r] += __shfl_xor(p2[r], off, 16);
    }
  if ((lane & 15) == 0) {
    int oc = ob * 64 + w * 16 + (lane >> 4) * 4;
    size_t base = (size_t)nd * OC + oc;
    #pragma unroll
    for (int r = 0; r < 4; ++r) { S1[base + r] = p1[r]; S2[base + r] = p2[r]; }
  }
}

// ---------------- epilogue head (unchanged from passing version) ----------------
__global__ void head_kernel(const float* __restrict__ WvT, const float* __restrict__ sbuf,
                            const float* __restrict__ S1, const float* __restrict__ S2,
                            const float* __restrict__ gamma, const float* __restrict__ beta,
                            const float* __restrict__ Wout, const float* __restrict__ bout,
                            float* __restrict__ outs) {
  int b = blockIdx.x;
  int o = b & 3, nd = b >> 2;
  int t = threadIdx.x;
  __shared__ float ss[512];
  __shared__ float red[4];
  ss[t] = sbuf[((size_t)nd * 4 + o) * Cc + t];
  ss[t + 256] = sbuf[((size_t)nd * 4 + o) * Cc + t + 256];
  __syncthreads();
  float d0 = 0.f, d1 = 0.f;
  #pragma unroll 8
  for (int cp = 0; cp < Cc; ++cp) {
    const float* rowp = WvT + (size_t)cp * OC + o * Cc;
    float sv = ss[cp];
    d0 = fmaf(rowp[t], sv, d0);
    d1 = fmaf(rowp[t + 256], sv, d1);
  }
  float partial = 0.f;
  #pragma unroll
  for (int i = 0; i < 2; ++i) {
    int c = t + (i << 8);
    int oc = o * Cc + c;
    float m1 = S1[(size_t)nd * OC + oc] * INV196;
    float m2 = S2[(size_t)nd * OC + oc] * INV196;
    float var = m2 - m1 * m1;
    float rs = rsqrtf(var + 1e-5f);
    float dv = (i == 0) ? d0 : d1;
    float xh = (dv - m1) * rs * gamma[oc] + beta[oc];
    float ge = 0.5f * xh * (1.0f + erff(xh * 0.70710678118654752f));
    partial = fmaf(ge, Wout[o * Cc + c], partial);
  }
  float s = partial;
  #pragma unroll
  for (int off = 32; off; off >>= 1) s += __shfl_down(s, off, 64);
  if ((t & 63) == 0) red[t >> 6] = s;
  __syncthreads();
  if (t == 0) {
    int n = nd >> 5, d = nd & 31;
    outs[o * 64 + n * 32 + d] = red[0] + red[1] + red[2] + red[3] + bout[o];
  }
}

}  // namespace

extern "C" void kernel_launch(void* const* d_in, const int* in_sizes, int n_in,
                              void* d_out, int out_size, void* d_ws, size_t ws_size,
                              hipStream_t stream) {
  const float* x     = (const float*)d_in[0];
  const float* Wq    = (const float*)d_in[1];
  const float* Wk    = (const float*)d_in[2];
  const float* Wv    = (const float*)d_in[3];
  const float* gamma = (const float*)d_in[4];
  const float* beta  = (const float*)d_in[5];
  const float* Wout  = (const float*)d_in[6];
  const float* bout  = (const float*)d_in[7];
  float* out      = (float*)d_out;
  float* attn_out = out;            // (N,4,D,196) = 50176 floats
  float* outs     = out + 50176;    // (4,N,1,D)   = 256 floats

  float* ws   = (float*)d_ws;
  float* WvT  = ws;                                // 1048576 f
  short* WvA  = (short*)(ws + 1048576);            // 2097152 shorts (1048576 f)
  short* xpPH = (short*)(ws + 2097152);            // 7340032 shorts (3670016 f)
  short* xpPL = (short*)(ws + 5767168);            // 7340032 shorts (3670016 f)
  float* xm   = ws + 9437184;                      // 32768 f
  float* qb   = ws + 9469952;                      // 2048 f
  float* sb   = ws + 9472000;                      // 131072 f
  float* S1   = ws + 9603072;                      // 131072 f
  float* S2   = ws + 9734144;                      // 131072 f

  transpose_k<<<256, 256, 0, stream>>>(Wv, WvT, 2048, 512);
  convert_wv<<<512, 256, 0, stream>>>(Wv, WvA);
  pool_kernel<<<4096, 256, 0, stream>>>(x, xpPH, xpPL, xm);
  query_kernel<<<64, 256, 0, stream>>>(Wq, xm, qb);
  attn_kernel<<<64, 256, 0, stream>>>(Wk, qb, xpPH, xpPL, attn_out, sb);
  moments_mfma<<<2048, 256, 0, stream>>>(WvA, xpPH, xpPL, S1, S2);
  head_kernel<<<256, 256, 0, stream>>>(WvT, sb, S1, S2, gamma, beta, Wout, bout, outs);
}

// Round 3
// 191.810 us; speedup vs baseline: 2.7059x; 1.3096x over previous
//
#include <hip/hip_runtime.h>
#include <math.h>

namespace {

constexpr int Cc  = 512;
constexpr int HW  = 196;
constexpr int HWP = 224;
constexpr int OC  = 2048;
constexpr float TEMP   = 0.35355339059327373f;  // 1/sqrt(KEY_DIM)
constexpr float INV196 = 1.0f / 196.0f;

typedef __attribute__((ext_vector_type(8))) short short8;
typedef __attribute__((ext_vector_type(4))) float f32x4;

__device__ __forceinline__ unsigned short f2bf(float x) {
  union { float f; unsigned int u; } v; v.f = x;
  unsigned int r = v.u + 0x7FFFu + ((v.u >> 16) & 1u);
  return (unsigned short)(r >> 16);
}
__device__ __forceinline__ float bf2f(unsigned short b) {
  union { unsigned int u; float f; } v; v.u = ((unsigned int)b) << 16;
  return v.f;
}

__device__ __forceinline__ void gload_lds16(const void* g, void* l) {
  __builtin_amdgcn_global_load_lds(
      (const __attribute__((address_space(1))) void*)g,
      (__attribute__((address_space(3))) void*)l, 16, 0, 0);
}

#define MFMA16(a, b, c) __builtin_amdgcn_mfma_f32_16x16x32_bf16((a), (b), (c), 0, 0, 0)

// ---------------- transpose (generic, 64x64 tiles) — builds WvT for head ----------------
__global__ void transpose_k(const float* __restrict__ src, float* __restrict__ dst,
                            int R, int Ccol) {
  __shared__ float tile[64][65];
  int nbc = (Ccol + 63) >> 6;
  int br = blockIdx.x / nbc, bc = blockIdx.x - br * nbc;
  int r0 = br << 6, c0 = bc << 6;
  int lc = threadIdx.x & 63, lr = threadIdx.x >> 6;
  for (int rr = lr; rr < 64; rr += 4) {
    int r = r0 + rr, c = c0 + lc;
    tile[rr][lc] = (r < R && c < Ccol) ? src[(size_t)r * Ccol + c] : 0.f;
  }
  __syncthreads();
  for (int rr = lr; rr < 64; rr += 4) {
    int c = c0 + rr, r = r0 + lc;
    if (c < Ccol && r < R) dst[(size_t)c * R + r] = tile[lc][rr];
  }
}

// ---------------- Wv -> bf16 hi/lo A-fragment layout ----------------
// WvA[kk(16)][hl(2)][r(128)][lane(64)][e(8)] ; oc = r*16+(lane&15), c = kk*32+(lane>>4)*8+e
__global__ void convert_wv(const float* __restrict__ Wv, short* __restrict__ WvA) {
  int bid = blockIdx.x;               // 512
  int t = threadIdx.x;
  int kk = bid >> 5;
  int r = ((bid & 31) << 2) + (t >> 6);
  int lane = t & 63;
  int oc = r * 16 + (lane & 15);
  int c0 = kk * 32 + (lane >> 4) * 8;
  const float* src = Wv + (size_t)oc * 512 + c0;
  float4 v0 = *(const float4*)src;
  float4 v1 = *(const float4*)(src + 4);
  float vals[8] = {v0.x, v0.y, v0.z, v0.w, v1.x, v1.y, v1.z, v1.w};
  short8 hi, lo;
  #pragma unroll
  for (int e = 0; e < 8; ++e) {
    unsigned short h = f2bf(vals[e]);
    float rem = vals[e] - bf2f(h);
    hi[e] = (short)h;
    lo[e] = (short)f2bf(rem);
  }
  *(short8*)(WvA + ((size_t)(kk * 2 + 0) * 128 + r) * 512 + lane * 8) = hi;
  *(short8*)(WvA + ((size_t)(kk * 2 + 1) * 128 + r) * 512 + lane * 8) = lo;
}

// ---------------- avgpool 3x3 + spatial mean -> bf16 hi/lo xp in [nd][hw][c] ----------------
// grid: 64 nd * 64 cg blocks, 256 threads; 16B vector stores (one hw row-slice per thread)
__global__ void pool_kernel(const float* __restrict__ x, short* __restrict__ xpPH,
                            short* __restrict__ xpPL, float* __restrict__ xm) {
  int b = blockIdx.x;
  int cg = b & 63, nd = b >> 6;
  int n = nd >> 5, d = nd & 31;
  int c0 = cg * 8;
  int t = threadIdx.x;
  __shared__ float tl[8][264];
  int cl = t >> 5, s = t & 31;
  const float* xr = x + (((size_t)(n * 512 + c0 + cl)) * 32 + d) * 256;
  float4 va = *(const float4*)(xr + s * 8);
  float4 vb = *(const float4*)(xr + s * 8 + 4);
  *(float4*)&tl[cl][s * 8] = va;
  *(float4*)&tl[cl][s * 8 + 4] = vb;
  float rs = va.x + va.y + va.z + va.w + vb.x + vb.y + vb.z + vb.w;
  #pragma unroll
  for (int off = 16; off; off >>= 1) rs += __shfl_xor(rs, off, 32);
  if (s == 0) xm[nd * 512 + c0 + cl] = rs * (1.0f / 256.0f);
  __syncthreads();
  if (t < HWP) {
    int hw = t;
    short8 hi, lo;
    if (hw < HW) {
      int y = hw / 14, xx = hw - y * 14;
      #pragma unroll
      for (int c = 0; c < 8; ++c) {
        const float* q = &tl[c][y * 16 + xx];
        float val = (q[0] + q[1] + q[2] + q[16] + q[17] + q[18] +
                     q[32] + q[33] + q[34]) * (1.0f / 9.0f);
        unsigned short h = f2bf(val);
        hi[c] = (short)h;
        lo[c] = (short)f2bf(val - bf2f(h));
      }
    } else {
      #pragma unroll
      for (int c = 0; c < 8; ++c) { hi[c] = 0; lo[c] = 0; }
    }
    size_t off = ((size_t)nd * HWP + hw) * 512 + c0;
    *(short8*)(xpPH + off) = hi;
    *(short8*)(xpPL + off) = lo;
  }
}

// ---------------- attention: q, qw=q^T Wk, dot per pixel, softmax, s = xp@attn (per nd) ----------------
__global__ __launch_bounds__(256) void attn_kernel(
    const float* __restrict__ Wq, const float* __restrict__ Wk,
    const float* __restrict__ xm,
    const short* __restrict__ xpPH, const short* __restrict__ xpPL,
    float* __restrict__ attn_out, float* __restrict__ sbuf) {
  int nd = blockIdx.x;
  int t = threadIdx.x;
  __shared__ float xs[512];
  __shared__ float qs[32];
  __shared__ float qw[4][512];
  __shared__ float dot_l[4][256];
  __shared__ float attn_l[4][224];
  __shared__ float sred[4][512];
  xs[t] = xm[nd * Cc + t];
  xs[t + 256] = xm[nd * Cc + t + 256];
  __syncthreads();
  {
    int k = t >> 3, j = t & 7;
    float p = 0.f;
    #pragma unroll 8
    for (int c = j; c < Cc; c += 8) p = fmaf(Wq[k * Cc + c], xs[c], p);
    p += __shfl_xor(p, 4, 8);
    p += __shfl_xor(p, 2, 8);
    p += __shfl_xor(p, 1, 8);
    if (j == 0) qs[k] = p;
  }
  __syncthreads();
  {
    int o = t >> 6;
    int c0 = (t & 63) * 8;
    float q[8];
    #pragma unroll
    for (int kd = 0; kd < 8; ++kd) q[kd] = qs[o * 8 + kd];
    #pragma unroll
    for (int e = 0; e < 8; ++e) {
      float a = 0.f;
      #pragma unroll
      for (int kd = 0; kd < 8; ++kd) a = fmaf(q[kd], Wk[(size_t)(o * 8 + kd) * 512 + c0 + e], a);
      qw[o][c0 + e] = a;
    }
  }
  __syncthreads();
  float dot0 = 0.f, dot1 = 0.f, dot2 = 0.f, dot3 = 0.f;
  if (t < HWP) {
    const short8* rh = (const short8*)(xpPH + ((size_t)nd * HWP + t) * 512);
    const short8* rl = (const short8*)(xpPL + ((size_t)nd * HWP + t) * 512);
    for (int cb = 0; cb < 64; ++cb) {
      short8 h = rh[cb], l = rl[cb];
      #pragma unroll
      for (int e = 0; e < 8; ++e) {
        float xv = bf2f((unsigned short)h[e]) + bf2f((unsigned short)l[e]);
        dot0 = fmaf(qw[0][cb * 8 + e], xv, dot0);
        dot1 = fmaf(qw[1][cb * 8 + e], xv, dot1);
        dot2 = fmaf(qw[2][cb * 8 + e], xv, dot2);
        dot3 = fmaf(qw[3][cb * 8 + e], xv, dot3);
      }
    }
  }
  if (t < HW) {
    dot_l[0][t] = dot0 * TEMP;
    dot_l[1][t] = dot1 * TEMP;
    dot_l[2][t] = dot2 * TEMP;
    dot_l[3][t] = dot3 * TEMP;
  } else {
    #pragma unroll
    for (int o = 0; o < 4; ++o) dot_l[o][t] = -3.0e38f;
  }
  __syncthreads();
  {
    int o = t >> 6, l = t & 63;
    float v0 = dot_l[o][l], v1 = dot_l[o][l + 64], v2 = dot_l[o][l + 128], v3 = dot_l[o][l + 192];
    float m = fmaxf(fmaxf(v0, v1), fmaxf(v2, v3));
    #pragma unroll
    for (int off = 32; off; off >>= 1) m = fmaxf(m, __shfl_xor(m, off, 64));
    float e0 = expf(v0 - m), e1 = expf(v1 - m), e2 = expf(v2 - m), e3 = expf(v3 - m);
    float s = e0 + e1 + e2 + e3;
    #pragma unroll
    for (int off = 32; off; off >>= 1) s += __shfl_xor(s, off, 64);
    float inv = 1.0f / s;
    attn_l[o][l] = e0 * inv;
    attn_l[o][l + 64] = e1 * inv;
    attn_l[o][l + 128] = e2 * inv;
    if (l < 32) attn_l[o][l + 192] = e3 * inv;
    int n = nd >> 5, d = nd & 31;
    float* ao = attn_out + (((size_t)n * 4 + o) * 32 + d) * HW;
    ao[l] = e0 * inv;
    ao[l + 64] = e1 * inv;
    if (l + 128 < HW) ao[l + 128] = e2 * inv;
    if (l + 192 < HW) ao[l + 192] = e3 * inv;
  }
  __syncthreads();
  // phase B: s[o][c] = sum_hw attn[o][hw] * xp[hw][c]  (vectorized short8 loads)
  {
    int cgrp = t & 63, hg = t >> 6;
    int c0 = cgrp * 8;
    float sa[4][8];
    #pragma unroll
    for (int o = 0; o < 4; ++o)
      #pragma unroll
      for (int e = 0; e < 8; ++e) sa[o][e] = 0.f;
    const short* ph = xpPH + (size_t)nd * HWP * 512;
    const short* pl = xpPL + (size_t)nd * HWP * 512;
    for (int i = 0; i < 49; ++i) {
      int hw = hg + 4 * i;
      short8 h8 = *(const short8*)(ph + (size_t)hw * 512 + c0);
      short8 l8 = *(const short8*)(pl + (size_t)hw * 512 + c0);
      float a0 = attn_l[0][hw], a1 = attn_l[1][hw], a2 = attn_l[2][hw], a3 = attn_l[3][hw];
      #pragma unroll
      for (int e = 0; e < 8; ++e) {
        float xv = bf2f((unsigned short)h8[e]) + bf2f((unsigned short)l8[e]);
        sa[0][e] = fmaf(a0, xv, sa[0][e]);
        sa[1][e] = fmaf(a1, xv, sa[1][e]);
        sa[2][e] = fmaf(a2, xv, sa[2][e]);
        sa[3][e] = fmaf(a3, xv, sa[3][e]);
      }
    }
    if (hg == 0) {
      #pragma unroll
      for (int o = 0; o < 4; ++o)
        #pragma unroll
        for (int e = 0; e < 8; ++e) sred[o][c0 + e] = sa[o][e];
    }
    __syncthreads();
    #pragma unroll
    for (int g = 1; g < 4; ++g) {
      if (hg == g) {
        #pragma unroll
        for (int o = 0; o < 4; ++o)
          #pragma unroll
          for (int e = 0; e < 8; ++e) sred[o][c0 + e] += sa[o][e];
      }
      __syncthreads();
    }
    for (int i = t; i < 2048; i += 256) {
      int o = i >> 9, c = i & 511;
      sbuf[((size_t)nd * 4 + o) * 512 + c] = sred[o][c];
    }
  }
}

// ---------------- moments via split-bf16 MFMA ----------------
// grid 1024 blocks: nd = (bid>>7)*8 + (bid&7) [XCD-affine], ob = (bid>>3)&15.
// block tile 128 oc x 224 hw; 4 waves: wq = w>>1 (64-oc half), wh = w&1 (112-hw half).
// A: global->reg (prefetched); B: global_load_lds double-buffered, 1 barrier/kk.
__global__ __launch_bounds__(256, 2) void moments_mfma(
    const short* __restrict__ WvA, const short* __restrict__ xpPH,
    const short* __restrict__ xpPL, float* __restrict__ S1, float* __restrict__ S2) {
  int bid = blockIdx.x;
  int ob = (bid >> 3) & 15;
  int nd = ((bid >> 7) << 3) | (bid & 7);
  int t = threadIdx.x;
  int w = t >> 6, lane = t & 63;
  int wq = w >> 1, wh = w & 1;
  int rbase = ob * 8 + wq * 4;
  int jbase = wh * 7;
  __shared__ char ldsb[57344];   // 2 x 28 KB B buffers: [hl(2)][j(14)][cell(64)][16B]
  const size_t xbase = (size_t)nd * HWP * 512;
  const short* xph = xpPH + xbase;
  const short* xpl = xpPL + xbase;

  f32x4 acc[4][7];
  #pragma unroll
  for (int f = 0; f < 4; ++f)
    #pragma unroll
    for (int j = 0; j < 7; ++j) acc[f][j] = (f32x4){0.f, 0.f, 0.f, 0.f};

  int lhw = lane & 15, lc8 = lane >> 4;

  // prologue: stage kk=0 into buffer 0; load A for kk=0
  {
    int q0 = w * 7;
    #pragma unroll
    for (int i = 0; i < 7; ++i) {
      int q = q0 + i;
      int hl = q / 14, j = q - hl * 14;
      const short* src = (hl ? xpl : xph) + (size_t)(j * 16 + lhw) * 512 + lc8 * 8;
      gload_lds16((const void*)src, (void*)(ldsb + hl * 14336 + j * 1024));
    }
  }
  short8 ah[4], al[4], nah[4], nal[4];
  #pragma unroll
  for (int f = 0; f < 4; ++f) {
    ah[f] = *(const short8*)(WvA + ((size_t)(0 * 2 + 0) * 128 + rbase + f) * 512 + lane * 8);
    al[f] = *(const short8*)(WvA + ((size_t)(0 * 2 + 1) * 128 + rbase + f) * 512 + lane * 8);
  }
  __syncthreads();

  int cur = 0;
  for (int kk = 0; kk < 16; ++kk) {
    if (kk < 15) {
      // prefetch next A (global->reg)
      #pragma unroll
      for (int f = 0; f < 4; ++f) {
        nah[f] = *(const short8*)(WvA + ((size_t)((kk + 1) * 2 + 0) * 128 + rbase + f) * 512 + lane * 8);
        nal[f] = *(const short8*)(WvA + ((size_t)((kk + 1) * 2 + 1) * 128 + rbase + f) * 512 + lane * 8);
      }
      // stage next B into other buffer
      char* pbuf = ldsb + (cur ^ 1) * 28672;
      int q0 = w * 7;
      int kp32 = (kk + 1) * 32;
      #pragma unroll
      for (int i = 0; i < 7; ++i) {
        int q = q0 + i;
        int hl = q / 14, j = q - hl * 14;
        const short* src = (hl ? xpl : xph) + (size_t)(j * 16 + lhw) * 512 + kp32 + lc8 * 8;
        gload_lds16((const void*)src, (void*)(pbuf + hl * 14336 + j * 1024));
      }
    }
    // compute from current buffer
    const short* bhp = (const short*)(ldsb + cur * 28672);
    const short* blp = (const short*)(ldsb + cur * 28672 + 14336);
    #pragma unroll
    for (int j = 0; j < 7; ++j) {
      short8 bh = *(const short8*)(bhp + (jbase + j) * 512 + lane * 8);
      short8 bl = *(const short8*)(blp + (jbase + j) * 512 + lane * 8);
      #pragma unroll
      for (int f = 0; f < 4; ++f) {
        acc[f][j] = MFMA16(ah[f], bh, acc[f][j]);
        acc[f][j] = MFMA16(al[f], bh, acc[f][j]);
        acc[f][j] = MFMA16(ah[f], bl, acc[f][j]);
      }
    }
    __syncthreads();
    cur ^= 1;
    #pragma unroll
    for (int f = 0; f < 4; ++f) { ah[f] = nah[f]; al[f] = nal[f]; }
  }

  // epilogue: S1 = sum_hw v, S2 = sum_hw v^2 ; combine wh halves via LDS
  float* red = (float*)ldsb;   // [2]: S1/S2 x [wq(2)][64]
  float q1[4][4], q2[4][4];
  #pragma unroll
  for (int f = 0; f < 4; ++f) {
    #pragma unroll
    for (int r = 0; r < 4; ++r) {
      float u = 0.f, vsq = 0.f;
      #pragma unroll
      for (int j = 0; j < 7; ++j) {
        float v = acc[f][j][r];
        u += v;
        vsq = fmaf(v, v, vsq);
      }
      #pragma unroll
      for (int off = 8; off; off >>= 1) {
        u += __shfl_xor(u, off, 16);
        vsq += __shfl_xor(vsq, off, 16);
      }
      q1[f][r] = u; q2[f][r] = vsq;
    }
  }
  int rowq = lane >> 4;
  bool wr = (lane & 15) == 0;
  if (wh == 0 && wr) {
    #pragma unroll
    for (int f = 0; f < 4; ++f)
      #pragma unroll
      for (int r = 0; r < 4; ++r) {
        int idx = wq * 64 + f * 16 + rowq * 4 + r;
        red[idx] = q1[f][r];
        red[128 + idx] = q2[f][r];
      }
  }
  __syncthreads();
  if (wh == 1 && wr) {
    size_t base = (size_t)nd * OC + ob * 128 + wq * 64;
    #pragma unroll
    for (int f = 0; f < 4; ++f)
      #pragma unroll
      for (int r = 0; r < 4; ++r) {
        int idx = f * 16 + rowq * 4 + r;
        S1[base + idx] = red[wq * 64 + idx] + q1[f][r];
        S2[base + idx] = red[128 + wq * 64 + idx] + q2[f][r];
      }
  }
}

// ---------------- epilogue head ----------------
__global__ void head_kernel(const float* __restrict__ WvT, const float* __restrict__ sbuf,
                            const float* __restrict__ S1, const float* __restrict__ S2,
                            const float* __restrict__ gamma, const float* __restrict__ beta,
                            const float* __restrict__ Wout, const float* __restrict__ bout,
                            float* __restrict__ outs) {
  int b = blockIdx.x;
  int o = b & 3, nd = b >> 2;
  int t = threadIdx.x;
  __shared__ float ss[512];
  __shared__ float red[4];
  ss[t] = sbuf[((size_t)nd * 4 + o) * Cc + t];
  ss[t + 256] = sbuf[((size_t)nd * 4 + o) * Cc + t + 256];
  __syncthreads();
  float d0 = 0.f, d1 = 0.f;
  #pragma unroll 8
  for (int cp = 0; cp < Cc; ++cp) {
    const float* rowp = WvT + (size_t)cp * OC + o * Cc;
    float sv = ss[cp];
    d0 = fmaf(rowp[t], sv, d0);
    d1 = fmaf(rowp[t + 256], sv, d1);
  }
  float partial = 0.f;
  #pragma unroll
  for (int i = 0; i < 2; ++i) {
    int c = t + (i << 8);
    int oc = o * Cc + c;
    float m1 = S1[(size_t)nd * OC + oc] * INV196;
    float m2 = S2[(size_t)nd * OC + oc] * INV196;
    float var = m2 - m1 * m1;
    float rs = rsqrtf(var + 1e-5f);
    float dv = (i == 0) ? d0 : d1;
    float xh = (dv - m1) * rs * gamma[oc] + beta[oc];
    float ge = 0.5f * xh * (1.0f + erff(xh * 0.70710678118654752f));
    partial = fmaf(ge, Wout[o * Cc + c], partial);
  }
  float s = partial;
  #pragma unroll
  for (int off = 32; off; off >>= 1) s += __shfl_down(s, off, 64);
  if ((t & 63) == 0) red[t >> 6] = s;
  __syncthreads();
  if (t == 0) {
    int n = nd >> 5, d = nd & 31;
    outs[o * 64 + n * 32 + d] = red[0] + red[1] + red[2] + red[3] + bout[o];
  }
}

}  // namespace

extern "C" void kernel_launch(void* const* d_in, const int* in_sizes, int n_in,
                              void* d_out, int out_size, void* d_ws, size_t ws_size,
                              hipStream_t stream) {
  const float* x     = (const float*)d_in[0];
  const float* Wq    = (const float*)d_in[1];
  const float* Wk    = (const float*)d_in[2];
  const float* Wv    = (const float*)d_in[3];
  const float* gamma = (const float*)d_in[4];
  const float* beta  = (const float*)d_in[5];
  const float* Wout  = (const float*)d_in[6];
  const float* bout  = (const float*)d_in[7];
  float* out      = (float*)d_out;
  float* attn_out = out;            // (N,4,D,196) = 50176 floats
  float* outs     = out + 50176;    // (4,N,1,D)   = 256 floats

  float* ws   = (float*)d_ws;
  float* WvT  = ws;                                // 1048576 f
  short* WvA  = (short*)(ws + 1048576);            // 2097152 shorts
  short* xpPH = (short*)(ws + 2097152);            // 7340032 shorts
  short* xpPL = (short*)(ws + 5767168);            // 7340032 shorts
  float* xm   = ws + 9437184;                      // 32768 f
  float* sb   = ws + 9472000;                      // 131072 f
  float* S1   = ws + 9603072;                      // 131072 f
  float* S2   = ws + 9734144;                      // 131072 f

  transpose_k<<<256, 256, 0, stream>>>(Wv, WvT, 2048, 512);
  convert_wv<<<512, 256, 0, stream>>>(Wv, WvA);
  pool_kernel<<<4096, 256, 0, stream>>>(x, xpPH, xpPL, xm);
  attn_kernel<<<64, 256, 0, stream>>>(Wq, Wk, xm, xpPH, xpPL, attn_out, sb);
  moments_mfma<<<1024, 256, 0, stream>>>(WvA, xpPH, xpPL, S1, S2);
  head_kernel<<<256, 256, 0, stream>>>(WvT, sb, S1, S2, gamma, beta, Wout, bout, outs);
}

// Round 5
// 158.252 us; speedup vs baseline: 3.2797x; 1.2121x over previous
//
#include <hip/hip_runtime.h>
#include <math.h>

namespace {

constexpr int Cc  = 512;
constexpr int HW  = 196;
constexpr int HWP = 224;
constexpr int OC  = 2048;
constexpr float TEMP   = 0.35355339059327373f;  // 1/sqrt(KEY_DIM)
constexpr float INV196 = 1.0f / 196.0f;

typedef __attribute__((ext_vector_type(8))) _Float16 half8;
typedef __attribute__((ext_vector_type(2))) _Float16 half2v;
typedef __attribute__((ext_vector_type(4))) float f32x4;

__device__ __forceinline__ void gload_lds16(const void* g, void* l) {
  __builtin_amdgcn_global_load_lds(
      (const __attribute__((address_space(1))) void*)g,
      (__attribute__((address_space(3))) void*)l, 16, 0, 0);
}

#define MFMAH(a, b, c) __builtin_amdgcn_mfma_f32_16x16x32_f16((a), (b), (c), 0, 0, 0)

// ---------------- transpose (generic, 64x64 tiles) — builds WvT for head ----------------
__global__ void transpose_k(const float* __restrict__ src, float* __restrict__ dst,
                            int R, int Ccol) {
  __shared__ float tile[64][65];
  int nbc = (Ccol + 63) >> 6;
  int br = blockIdx.x / nbc, bc = blockIdx.x - br * nbc;
  int r0 = br << 6, c0 = bc << 6;
  int lc = threadIdx.x & 63, lr = threadIdx.x >> 6;
  for (int rr = lr; rr < 64; rr += 4) {
    int r = r0 + rr, c = c0 + lc;
    tile[rr][lc] = (r < R && c < Ccol) ? src[(size_t)r * Ccol + c] : 0.f;
  }
  __syncthreads();
  for (int rr = lr; rr < 64; rr += 4) {
    int c = c0 + rr, r = r0 + lc;
    if (c < Ccol && r < R) dst[(size_t)c * R + r] = tile[lc][rr];
  }
}

// ---------------- Wv -> f16 hi/lo A-fragment layout ----------------
// WvA[kk(16)][hl(2)][r(128)][lane(64)][e(8)] ; oc = r*16+(lane&15), c = kk*32+(lane>>4)*8+e
__global__ void convert_wv(const float* __restrict__ Wv, _Float16* __restrict__ WvA) {
  int bid = blockIdx.x;               // 512
  int t = threadIdx.x;
  int kk = bid >> 5;
  int r = ((bid & 31) << 2) + (t >> 6);
  int lane = t & 63;
  int oc = r * 16 + (lane & 15);
  int c0 = kk * 32 + (lane >> 4) * 8;
  const float* src = Wv + (size_t)oc * 512 + c0;
  float4 v0 = *(const float4*)src;
  float4 v1 = *(const float4*)(src + 4);
  float vals[8] = {v0.x, v0.y, v0.z, v0.w, v1.x, v1.y, v1.z, v1.w};
  half8 hi, lo;
  #pragma unroll
  for (int e = 0; e < 8; ++e) {
    _Float16 h = (_Float16)vals[e];
    hi[e] = h;
    lo[e] = (_Float16)(vals[e] - (float)h);
  }
  *(half8*)(WvA + ((size_t)(kk * 2 + 0) * 128 + r) * 512 + lane * 8) = hi;
  *(half8*)(WvA + ((size_t)(kk * 2 + 1) * 128 + r) * 512 + lane * 8) = lo;
}

// ---------------- avgpool 3x3 + spatial mean -> f16 hi/lo xp in [nd][hw][c] ----------------
__global__ void pool_kernel(const float* __restrict__ x, _Float16* __restrict__ xpH,
                            _Float16* __restrict__ xpL, float* __restrict__ xm) {
  int b = blockIdx.x;
  int cg = b & 63, nd = b >> 6;
  int n = nd >> 5, d = nd & 31;
  int c0 = cg * 8;
  int t = threadIdx.x;
  __shared__ float tl[8][264];
  int cl = t >> 5, s = t & 31;
  const float* xr = x + (((size_t)(n * 512 + c0 + cl)) * 32 + d) * 256;
  float4 va = *(const float4*)(xr + s * 8);
  float4 vb = *(const float4*)(xr + s * 8 + 4);
  *(float4*)&tl[cl][s * 8] = va;
  *(float4*)&tl[cl][s * 8 + 4] = vb;
  float rs = va.x + va.y + va.z + va.w + vb.x + vb.y + vb.z + vb.w;
  #pragma unroll
  for (int off = 16; off; off >>= 1) rs += __shfl_xor(rs, off, 32);
  if (s == 0) xm[nd * 512 + c0 + cl] = rs * (1.0f / 256.0f);
  __syncthreads();
  if (t < HWP) {
    int hw = t;
    half8 hi, lo;
    if (hw < HW) {
      int y = hw / 14, xx = hw - y * 14;
      #pragma unroll
      for (int c = 0; c < 8; ++c) {
        const float* q = &tl[c][y * 16 + xx];
        float val = (q[0] + q[1] + q[2] + q[16] + q[17] + q[18] +
                     q[32] + q[33] + q[34]) * (1.0f / 9.0f);
        _Float16 h = (_Float16)val;
        hi[c] = h;
        lo[c] = (_Float16)(val - (float)h);
      }
    } else {
      #pragma unroll
      for (int c = 0; c < 8; ++c) { hi[c] = (_Float16)0.f; lo[c] = (_Float16)0.f; }
    }
    size_t off = ((size_t)nd * HWP + hw) * 512 + c0;
    *(half8*)(xpH + off) = hi;
    *(half8*)(xpL + off) = lo;
  }
}

// ---------------- qw[nd][o][c] = (Wq @ xm)^T Wk ----------------
__global__ void qw_kernel(const float* __restrict__ Wq, const float* __restrict__ Wk,
                          const float* __restrict__ xm, float* __restrict__ qwb) {
  int nd = blockIdx.x;
  int t = threadIdx.x;
  __shared__ float xs[512];
  __shared__ float qs[32];
  xs[t] = xm[nd * Cc + t];
  xs[t + 256] = xm[nd * Cc + t + 256];
  __syncthreads();
  {
    int k = t >> 3, j = t & 7;
    float p = 0.f;
    #pragma unroll 8
    for (int c = j; c < Cc; c += 8) p = fmaf(Wq[k * Cc + c], xs[c], p);
    p += __shfl_xor(p, 4, 8);
    p += __shfl_xor(p, 2, 8);
    p += __shfl_xor(p, 1, 8);
    if (j == 0) qs[k] = p;
  }
  __syncthreads();
  {
    int o = t >> 6;
    int c0 = (t & 63) * 8;
    float q[8];
    #pragma unroll
    for (int kd = 0; kd < 8; ++kd) q[kd] = qs[o * 8 + kd];
    #pragma unroll
    for (int e = 0; e < 8; ++e) {
      float a = 0.f;
      #pragma unroll
      for (int kd = 0; kd < 8; ++kd)
        a = fmaf(q[kd], Wk[(size_t)(o * 8 + kd) * 512 + c0 + e], a);
      qwb[(size_t)nd * 2048 + o * 512 + c0 + e] = a;
    }
  }
}

// ---------------- dots: dot[nd][o][hw] = qw[o] . xp[hw]  (4 lanes per hw) ----------------
__global__ __launch_bounds__(256) void qk_dot(const float* __restrict__ qwb,
                                              const _Float16* __restrict__ xpH,
                                              const _Float16* __restrict__ xpL,
                                              float* __restrict__ dotb) {
  int b = blockIdx.x;
  int nd = b >> 2, ch = b & 3;
  int t = threadIdx.x;
  __shared__ float qw[2048];
  for (int i = t; i < 2048; i += 256) qw[i] = qwb[(size_t)nd * 2048 + i];
  __syncthreads();
  if (t < 224) {
    int hwl = t >> 2, q = t & 3;
    int hw = ch * 56 + hwl;
    const _Float16* rh = xpH + ((size_t)nd * HWP + hw) * 512;
    const _Float16* rl = xpL + ((size_t)nd * HWP + hw) * 512;
    float d0 = 0.f, d1 = 0.f, d2 = 0.f, d3 = 0.f;
    #pragma unroll
    for (int k = 0; k < 16; ++k) {
      int cb = q * 8 + k * 32;           // interleaved c-blocks: conflict-free qw banks
      half8 h = *(const half8*)(rh + cb);
      half8 l = *(const half8*)(rl + cb);
      #pragma unroll
      for (int e = 0; e < 8; ++e) {
        float xv = (float)h[e] + (float)l[e];
        d0 = fmaf(qw[cb + e], xv, d0);
        d1 = fmaf(qw[512 + cb + e], xv, d1);
        d2 = fmaf(qw[1024 + cb + e], xv, d2);
        d3 = fmaf(qw[1536 + cb + e], xv, d3);
      }
    }
    d0 += __shfl_xor(d0, 1, 4); d0 += __shfl_xor(d0, 2, 4);
    d1 += __shfl_xor(d1, 1, 4); d1 += __shfl_xor(d1, 2, 4);
    d2 += __shfl_xor(d2, 1, 4); d2 += __shfl_xor(d2, 2, 4);
    d3 += __shfl_xor(d3, 1, 4); d3 += __shfl_xor(d3, 2, 4);
    float r = (q == 0) ? d0 : (q == 1) ? d1 : (q == 2) ? d2 : d3;
    dotb[((size_t)nd * 4 + q) * HWP + hw] = r * TEMP;
  }
}

// ---------------- softmax per (nd,o); exact division to match np ulp ----------------
__global__ void softmax_kernel(const float* __restrict__ dotb, float* __restrict__ attn_out) {
  int b = blockIdx.x;          // nd*4 + o
  int nd = b >> 2, o = b & 3;
  int t = threadIdx.x;
  int w = t >> 6, lane = t & 63;
  __shared__ float redm[4];
  __shared__ float reds[4];
  float v = (t < HW) ? dotb[(size_t)b * HWP + t] : -3.0e38f;
  float m = v;
  #pragma unroll
  for (int off = 32; off; off >>= 1) m = fmaxf(m, __shfl_xor(m, off, 64));
  if (lane == 0) redm[w] = m;
  __syncthreads();
  float bm = fmaxf(fmaxf(redm[0], redm[1]), fmaxf(redm[2], redm[3]));
  float e = (t < HW) ? expf(v - bm) : 0.f;
  float s = e;
  #pragma unroll
  for (int off = 32; off; off >>= 1) s += __shfl_xor(s, off, 64);
  if (lane == 0) reds[w] = s;
  __syncthreads();
  float bs = reds[0] + reds[1] + reds[2] + reds[3];
  if (t < HW) {
    int n = nd >> 5, d = nd & 31;
    attn_out[(((size_t)n * 4 + o) * 32 + d) * HW + t] = e / bs;
  }
}

// ---------------- s[nd][o][c] = sum_hw attn * xp   (per (nd, c-quarter)) ----------------
__global__ __launch_bounds__(256) void s_kernel(const _Float16* __restrict__ xpH,
                                                const _Float16* __restrict__ xpL,
                                                const float* __restrict__ attn_out,
                                                float* __restrict__ sbuf) {
  int b = blockIdx.x;
  int nd = b >> 2, cq = b & 3;
  int c0 = cq * 128;
  int t = threadIdx.x;
  int w = t >> 6, lane = t & 63;
  int n = nd >> 5, d = nd & 31;
  __shared__ float al[4][196];
  __shared__ float sred[4][4][128];
  #pragma unroll
  for (int o = 0; o < 4; ++o)
    if (t < HW) al[o][t] = attn_out[(((size_t)n * 4 + o) * 32 + d) * HW + t];
  __syncthreads();
  float a00 = 0.f, a01 = 0.f, a10 = 0.f, a11 = 0.f;
  float a20 = 0.f, a21 = 0.f, a30 = 0.f, a31 = 0.f;
  for (int hw = w; hw < HW; hw += 4) {
    size_t off = ((size_t)nd * HWP + hw) * 512 + c0 + lane * 2;
    half2v h = *(const half2v*)(xpH + off);
    half2v l = *(const half2v*)(xpL + off);
    float x0 = (float)h[0] + (float)l[0];
    float x1 = (float)h[1] + (float)l[1];
    float t0 = al[0][hw], t1 = al[1][hw], t2 = al[2][hw], t3 = al[3][hw];
    a00 = fmaf(t0, x0, a00); a01 = fmaf(t0, x1, a01);
    a10 = fmaf(t1, x0, a10); a11 = fmaf(t1, x1, a11);
    a20 = fmaf(t2, x0, a20); a21 = fmaf(t2, x1, a21);
    a30 = fmaf(t3, x0, a30); a31 = fmaf(t3, x1, a31);
  }
  sred[w][0][lane * 2] = a00; sred[w][0][lane * 2 + 1] = a01;
  sred[w][1][lane * 2] = a10; sred[w][1][lane * 2 + 1] = a11;
  sred[w][2][lane * 2] = a20; sred[w][2][lane * 2 + 1] = a21;
  sred[w][3][lane * 2] = a30; sred[w][3][lane * 2 + 1] = a31;
  __syncthreads();
  #pragma unroll
  for (int i = 0; i < 2; ++i) {
    int idx = t + i * 256;
    int o = idx >> 7, c = idx & 127;
    float s = sred[0][o][c] + sred[1][o][c] + sred[2][o][c] + sred[3][o][c];
    sbuf[((size_t)nd * 4 + o) * 512 + c0 + c] = s;
  }
}

// ---------------- moments via 2-product f16 MFMA: per-(nd,oc) S1,S2 of v = Wv @ xp ----------------
// grid 1024: nd-XCD-affine; block tile 128 oc x 224 hw; waves: wq (oc half) x wh (hw half).
// A: f16 hi/lo pair global->reg prefetched; B: f16 hi only, global_load_lds dbuf, 1 barrier/kk.
// LDS j-block = 1024B = 64 granules of 16B; granule index within j == lane, so granule g
// must hold xp[hw = j*16 + (g&15)][c = kk*32 + (g>>4)*8 ..+8]  (g&15 / g>>4 — NOT g>>2/g&3).
__global__ __launch_bounds__(256, 2) void moments_mfma(
    const _Float16* __restrict__ WvA, const _Float16* __restrict__ xpH,
    float* __restrict__ S1, float* __restrict__ S2) {
  int bid = blockIdx.x;
  int ob = (bid >> 3) & 15;
  int nd = ((bid >> 7) << 3) | (bid & 7);
  int t = threadIdx.x;
  int w = t >> 6, lane = t & 63;
  int wq = w >> 1, wh = w & 1;
  int rbase = ob * 8 + wq * 4;
  int jbase = wh * 7;
  __shared__ char ldsb[28672];   // 2 x 14 KB B buffers: [j(14)][granule(64)][16B]
  const _Float16* xph = xpH + (size_t)nd * HWP * 512;

  f32x4 acc[4][7];
  #pragma unroll
  for (int f = 0; f < 4; ++f)
    #pragma unroll
    for (int j = 0; j < 7; ++j) acc[f][j] = (f32x4){0.f, 0.f, 0.f, 0.f};

  // stage B tile for kk into buffer: 896 granules = 3.5 block-wide 16B issues
  auto stage = [&](char* buf, int kk) {
    #pragma unroll
    for (int i = 0; i < 4; ++i) {
      if (i < 3 || t < 128) {
        int G = i * 256 + t;
        int j = G >> 6;
        int g = G & 63;              // == lane
        int hwl = g & 15, bb = g >> 4;
        const _Float16* src = xph + (size_t)(j * 16 + hwl) * 512 + kk * 32 + bb * 8;
        gload_lds16((const void*)src, (void*)(buf + G * 16));
      }
    }
  };

  stage(ldsb, 0);
  half8 ah[4], al[4], nah[4], nal[4];
  #pragma unroll
  for (int f = 0; f < 4; ++f) {
    ah[f] = *(const half8*)(WvA + ((size_t)0 * 128 + rbase + f) * 512 + lane * 8);
    al[f] = *(const half8*)(WvA + ((size_t)1 * 128 + rbase + f) * 512 + lane * 8);
  }
  __syncthreads();

  int cur = 0;
  for (int kk = 0; kk < 16; ++kk) {
    if (kk < 15) {
      #pragma unroll
      for (int f = 0; f < 4; ++f) {
        nah[f] = *(const half8*)(WvA + ((size_t)((kk + 1) * 2 + 0) * 128 + rbase + f) * 512 + lane * 8);
        nal[f] = *(const half8*)(WvA + ((size_t)((kk + 1) * 2 + 1) * 128 + rbase + f) * 512 + lane * 8);
      }
      stage(ldsb + (cur ^ 1) * 14336, kk + 1);
    }
    const char* bp = ldsb + cur * 14336;
    #pragma unroll
    for (int j = 0; j < 7; ++j) {
      half8 bh = *(const half8*)(bp + (jbase + j) * 1024 + lane * 16);
      #pragma unroll
      for (int f = 0; f < 4; ++f) {
        acc[f][j] = MFMAH(ah[f], bh, acc[f][j]);
        acc[f][j] = MFMAH(al[f], bh, acc[f][j]);
      }
    }
    __syncthreads();
    cur ^= 1;
    #pragma unroll
    for (int f = 0; f < 4; ++f) { ah[f] = nah[f]; al[f] = nal[f]; }
  }

  // epilogue: S1 = sum_hw v, S2 = sum_hw v^2 ; combine wh halves via LDS
  float* red = (float*)ldsb;
  float q1[4][4], q2[4][4];
  #pragma unroll
  for (int f = 0; f < 4; ++f) {
    #pragma unroll
    for (int r = 0; r < 4; ++r) {
      float u = 0.f, vsq = 0.f;
      #pragma unroll
      for (int j = 0; j < 7; ++j) {
        float v = acc[f][j][r];
        u += v;
        vsq = fmaf(v, v, vsq);
      }
      #pragma unroll
      for (int off = 8; off; off >>= 1) {
        u += __shfl_xor(u, off, 16);
        vsq += __shfl_xor(vsq, off, 16);
      }
      q1[f][r] = u; q2[f][r] = vsq;
    }
  }
  int rowq = lane >> 4;
  bool wr = (lane & 15) == 0;
  if (wh == 0 && wr) {
    #pragma unroll
    for (int f = 0; f < 4; ++f)
      #pragma unroll
      for (int r = 0; r < 4; ++r) {
        int idx = wq * 64 + f * 16 + rowq * 4 + r;
        red[idx] = q1[f][r];
        red[128 + idx] = q2[f][r];
      }
  }
  __syncthreads();
  if (wh == 1 && wr) {
    size_t base = (size_t)nd * OC + ob * 128 + wq * 64;
    #pragma unroll
    for (int f = 0; f < 4; ++f)
      #pragma unroll
      for (int r = 0; r < 4; ++r) {
        int idx = f * 16 + rowq * 4 + r;
        S1[base + idx] = red[wq * 64 + idx] + q1[f][r];
        S2[base + idx] = red[128 + wq * 64 + idx] + q2[f][r];
      }
  }
}

// ---------------- epilogue head ----------------
__global__ void head_kernel(const float* __restrict__ WvT, const float* __restrict__ sbuf,
                            const float* __restrict__ S1, const float* __restrict__ S2,
                            const float* __restrict__ gamma, const float* __restrict__ beta,
                            const float* __restrict__ Wout, const float* __restrict__ bout,
                            float* __restrict__ outs) {
  int b = blockIdx.x;
  int o = b & 3, nd = b >> 2;
  int t = threadIdx.x;
  __shared__ float ss[512];
  __shared__ float red[4];
  ss[t] = sbuf[((size_t)nd * 4 + o) * Cc + t];
  ss[t + 256] = sbuf[((size_t)nd * 4 + o) * Cc + t + 256];
  __syncthreads();
  float d0 = 0.f, d1 = 0.f;
  #pragma unroll 8
  for (int cp = 0; cp < Cc; ++cp) {
    const float* rowp = WvT + (size_t)cp * OC + o * Cc;
    float sv = ss[cp];
    d0 = fmaf(rowp[t], sv, d0);
    d1 = fmaf(rowp[t + 256], sv, d1);
  }
  float partial = 0.f;
  #pragma unroll
  for (int i = 0; i < 2; ++i) {
    int c = t + (i << 8);
    int oc = o * Cc + c;
    float m1 = S1[(size_t)nd * OC + oc] * INV196;
    float m2 = S2[(size_t)nd * OC + oc] * INV196;
    float var = m2 - m1 * m1;
    float rs = rsqrtf(var + 1e-5f);
    float dv = (i == 0) ? d0 : d1;
    float xh = (dv - m1) * rs * gamma[oc] + beta[oc];
    float ge = 0.5f * xh * (1.0f + erff(xh * 0.70710678118654752f));
    partial = fmaf(ge, Wout[o * Cc + c], partial);
  }
  float s = partial;
  #pragma unroll
  for (int off = 32; off; off >>= 1) s += __shfl_down(s, off, 64);
  if ((t & 63) == 0) red[t >> 6] = s;
  __syncthreads();
  if (t == 0) {
    int n = nd >> 5, d = nd & 31;
    outs[o * 64 + n * 32 + d] = red[0] + red[1] + red[2] + red[3] + bout[o];
  }
}

}  // namespace

extern "C" void kernel_launch(void* const* d_in, const int* in_sizes, int n_in,
                              void* d_out, int out_size, void* d_ws, size_t ws_size,
                              hipStream_t stream) {
  const float* x     = (const float*)d_in[0];
  const float* Wq    = (const float*)d_in[1];
  const float* Wk    = (const float*)d_in[2];
  const float* Wv    = (const float*)d_in[3];
  const float* gamma = (const float*)d_in[4];
  const float* beta  = (const float*)d_in[5];
  const float* Wout  = (const float*)d_in[6];
  const float* bout  = (const float*)d_in[7];
  float* out      = (float*)d_out;
  float* attn_out = out;            // (N,4,D,196) = 50176 floats
  float* outs     = out + 50176;    // (4,N,1,D)   = 256 floats

  float* ws = (float*)d_ws;
  float*     WvT = ws;                                  // [0, 1048576)
  _Float16*  WvA = (_Float16*)(ws + 1048576);           // 2097152 f16 -> [1048576, 2097152)
  _Float16*  xpH = (_Float16*)(ws + 2097152);           // 7340032 f16 -> [2097152, 5767168)
  _Float16*  xpL = (_Float16*)(ws + 5767168);           // 7340032 f16 -> [5767168, 9437184)
  float*     xm  = ws + 9437184;                        // 32768
  float*     qwb = ws + 9469952;                        // 131072
  float*     dotb= ws + 9601024;                        // 57344
  float*     sb  = ws + 9658368;                        // 131072
  float*     S1  = ws + 9789440;                        // 131072
  float*     S2  = ws + 9920512;                        // 131072

  transpose_k<<<256, 256, 0, stream>>>(Wv, WvT, 2048, 512);
  convert_wv<<<512, 256, 0, stream>>>(Wv, WvA);
  pool_kernel<<<4096, 256, 0, stream>>>(x, xpH, xpL, xm);
  qw_kernel<<<64, 256, 0, stream>>>(Wq, Wk, xm, qwb);
  qk_dot<<<256, 256, 0, stream>>>(qwb, xpH, xpL, dotb);
  softmax_kernel<<<256, 256, 0, stream>>>(dotb, attn_out);
  s_kernel<<<256, 256, 0, stream>>>(xpH, xpL, attn_out, sb);
  moments_mfma<<<1024, 256, 0, stream>>>(WvA, xpH, S1, S2);
  head_kernel<<<256, 256, 0, stream>>>(WvT, sb, S1, S2, gamma, beta, Wout, bout, outs);
}

// Round 6
// 141.279 us; speedup vs baseline: 3.6737x; 1.1201x over previous
//
#include <hip/hip_runtime.h>
#include <math.h>

namespace {

constexpr int Cc  = 512;
constexpr int HW  = 196;
constexpr int HWP = 224;
constexpr int OC  = 2048;
constexpr float TEMP   = 0.35355339059327373f;  // 1/sqrt(KEY_DIM)
constexpr float INV196 = 1.0f / 196.0f;

typedef __attribute__((ext_vector_type(8))) _Float16 half8;
typedef __attribute__((ext_vector_type(2))) _Float16 half2v;
typedef __attribute__((ext_vector_type(4))) float f32x4;

__device__ __forceinline__ void gload_lds16(const void* g, void* l) {
  __builtin_amdgcn_global_load_lds(
      (const __attribute__((address_space(1))) void*)g,
      (__attribute__((address_space(3))) void*)l, 16, 0, 0);
}

#define MFMAH(a, b, c) __builtin_amdgcn_mfma_f32_16x16x32_f16((a), (b), (c), 0, 0, 0)

// ---------------- Wv -> f16 hi/lo A-fragment layout + WvT (fused) ----------------
// WvA[kk(16)][hl(2)][r(128)][lane(64)][e(8)] ; oc = r*16+(lane&15), c = kk*32+(lane>>4)*8+e
// Block tile = 64 oc x 32 c; also LDS-transposes tile into WvT[c][oc] coalesced.
__global__ void wv_prep(const float* __restrict__ Wv, _Float16* __restrict__ WvA,
                        float* __restrict__ WvT) {
  int bid = blockIdx.x;               // 512
  int t = threadIdx.x;
  int kk = bid >> 5;
  int rq = bid & 31;
  int w = t >> 6, lane = t & 63;
  int r = rq * 4 + w;
  int oc = r * 16 + (lane & 15);
  int c0 = kk * 32 + (lane >> 4) * 8;
  __shared__ float tile[64][33];
  const float* src = Wv + (size_t)oc * 512 + c0;
  float4 v0 = *(const float4*)src;
  float4 v1 = *(const float4*)(src + 4);
  float vals[8] = {v0.x, v0.y, v0.z, v0.w, v1.x, v1.y, v1.z, v1.w};
  half8 hi, lo;
  #pragma unroll
  for (int e = 0; e < 8; ++e) {
    _Float16 h = (_Float16)vals[e];
    hi[e] = h;
    lo[e] = (_Float16)(vals[e] - (float)h);
  }
  *(half8*)(WvA + ((size_t)(kk * 2 + 0) * 128 + r) * 512 + lane * 8) = hi;
  *(half8*)(WvA + ((size_t)(kk * 2 + 1) * 128 + r) * 512 + lane * 8) = lo;
  int ocl = w * 16 + (lane & 15);
  int cl = (lane >> 4) * 8;
  #pragma unroll
  for (int e = 0; e < 8; ++e) tile[ocl][cl + e] = vals[e];
  __syncthreads();
  int ocb = rq * 64;
  #pragma unroll
  for (int k2 = 0; k2 < 8; ++k2) {
    int idx = k2 * 256 + t;
    int c_l = idx >> 6, oc_l = idx & 63;
    WvT[(size_t)(kk * 32 + c_l) * 2048 + ocb + oc_l] = tile[oc_l][c_l];
  }
}

// ---------------- avgpool 3x3 + spatial mean -> f16 hi/lo xp in [nd][hw][c] ----------------
__global__ void pool_kernel(const float* __restrict__ x, _Float16* __restrict__ xpH,
                            _Float16* __restrict__ xpL, float* __restrict__ xm) {
  int b = blockIdx.x;
  int cg = b & 63, nd = b >> 6;
  int n = nd >> 5, d = nd & 31;
  int c0 = cg * 8;
  int t = threadIdx.x;
  __shared__ float tl[8][264];
  int cl = t >> 5, s = t & 31;
  const float* xr = x + (((size_t)(n * 512 + c0 + cl)) * 32 + d) * 256;
  float4 va = *(const float4*)(xr + s * 8);
  float4 vb = *(const float4*)(xr + s * 8 + 4);
  *(float4*)&tl[cl][s * 8] = va;
  *(float4*)&tl[cl][s * 8 + 4] = vb;
  float rs = va.x + va.y + va.z + va.w + vb.x + vb.y + vb.z + vb.w;
  #pragma unroll
  for (int off = 16; off; off >>= 1) rs += __shfl_xor(rs, off, 32);
  if (s == 0) xm[nd * 512 + c0 + cl] = rs * (1.0f / 256.0f);
  __syncthreads();
  if (t < HWP) {
    int hw = t;
    half8 hi, lo;
    if (hw < HW) {
      int y = hw / 14, xx = hw - y * 14;
      #pragma unroll
      for (int c = 0; c < 8; ++c) {
        const float* q = &tl[c][y * 16 + xx];
        float val = (q[0] + q[1] + q[2] + q[16] + q[17] + q[18] +
                     q[32] + q[33] + q[34]) * (1.0f / 9.0f);
        _Float16 h = (_Float16)val;
        hi[c] = h;
        lo[c] = (_Float16)(val - (float)h);
      }
    } else {
      #pragma unroll
      for (int c = 0; c < 8; ++c) { hi[c] = (_Float16)0.f; lo[c] = (_Float16)0.f; }
    }
    size_t off = ((size_t)nd * HWP + hw) * 512 + c0;
    *(half8*)(xpH + off) = hi;
    *(half8*)(xpL + off) = lo;
  }
}

// ---------------- moments via 2-product f16 MFMA: per-(nd,oc) S1,S2 of v = Wv @ xp ----------------
// grid 1024: nd-XCD-affine; block tile 128 oc x 224 hw; waves: wq (oc half) x wh (hw half).
// A: f16 hi/lo pair global->reg prefetched; B: f16 hi only, global_load_lds dbuf, 1 barrier/kk.
__global__ __launch_bounds__(256, 2) void moments_mfma(
    const _Float16* __restrict__ WvA, const _Float16* __restrict__ xpH,
    float* __restrict__ S1, float* __restrict__ S2) {
  int bid = blockIdx.x;
  int ob = (bid >> 3) & 15;
  int nd = ((bid >> 7) << 3) | (bid & 7);
  int t = threadIdx.x;
  int w = t >> 6, lane = t & 63;
  int wq = w >> 1, wh = w & 1;
  int rbase = ob * 8 + wq * 4;
  int jbase = wh * 7;
  __shared__ char ldsb[28672];   // 2 x 14 KB B buffers: [j(14)][granule(64)][16B]
  const _Float16* xph = xpH + (size_t)nd * HWP * 512;

  f32x4 acc[4][7];
  #pragma unroll
  for (int f = 0; f < 4; ++f)
    #pragma unroll
    for (int j = 0; j < 7; ++j) acc[f][j] = (f32x4){0.f, 0.f, 0.f, 0.f};

  auto stage = [&](char* buf, int kk) {
    #pragma unroll
    for (int i = 0; i < 4; ++i) {
      if (i < 3 || t < 128) {
        int G = i * 256 + t;
        int j = G >> 6;
        int g = G & 63;              // == lane
        int hwl = g & 15, bb = g >> 4;
        const _Float16* src = xph + (size_t)(j * 16 + hwl) * 512 + kk * 32 + bb * 8;
        gload_lds16((const void*)src, (void*)(buf + G * 16));
      }
    }
  };

  stage(ldsb, 0);
  half8 ah[4], al[4], nah[4], nal[4];
  #pragma unroll
  for (int f = 0; f < 4; ++f) {
    ah[f] = *(const half8*)(WvA + ((size_t)0 * 128 + rbase + f) * 512 + lane * 8);
    al[f] = *(const half8*)(WvA + ((size_t)1 * 128 + rbase + f) * 512 + lane * 8);
  }
  __syncthreads();

  int cur = 0;
  for (int kk = 0; kk < 16; ++kk) {
    if (kk < 15) {
      #pragma unroll
      for (int f = 0; f < 4; ++f) {
        nah[f] = *(const half8*)(WvA + ((size_t)((kk + 1) * 2 + 0) * 128 + rbase + f) * 512 + lane * 8);
        nal[f] = *(const half8*)(WvA + ((size_t)((kk + 1) * 2 + 1) * 128 + rbase + f) * 512 + lane * 8);
      }
      stage(ldsb + (cur ^ 1) * 14336, kk + 1);
    }
    const char* bp = ldsb + cur * 14336;
    #pragma unroll
    for (int j = 0; j < 7; ++j) {
      half8 bh = *(const half8*)(bp + (jbase + j) * 1024 + lane * 16);
      #pragma unroll
      for (int f = 0; f < 4; ++f) {
        acc[f][j] = MFMAH(ah[f], bh, acc[f][j]);
        acc[f][j] = MFMAH(al[f], bh, acc[f][j]);
      }
    }
    __syncthreads();
    cur ^= 1;
    #pragma unroll
    for (int f = 0; f < 4; ++f) { ah[f] = nah[f]; al[f] = nal[f]; }
  }

  float* red = (float*)ldsb;
  float q1[4][4], q2[4][4];
  #pragma unroll
  for (int f = 0; f < 4; ++f) {
    #pragma unroll
    for (int r = 0; r < 4; ++r) {
      float u = 0.f, vsq = 0.f;
      #pragma unroll
      for (int j = 0; j < 7; ++j) {
        float v = acc[f][j][r];
        u += v;
        vsq = fmaf(v, v, vsq);
      }
      #pragma unroll
      for (int off = 8; off; off >>= 1) {
        u += __shfl_xor(u, off, 16);
        vsq += __shfl_xor(vsq, off, 16);
      }
      q1[f][r] = u; q2[f][r] = vsq;
    }
  }
  int rowq = lane >> 4;
  bool wr = (lane & 15) == 0;
  if (wh == 0 && wr) {
    #pragma unroll
    for (int f = 0; f < 4; ++f)
      #pragma unroll
      for (int r = 0; r < 4; ++r) {
        int idx = wq * 64 + f * 16 + rowq * 4 + r;
        red[idx] = q1[f][r];
        red[128 + idx] = q2[f][r];
      }
  }
  __syncthreads();
  if (wh == 1 && wr) {
    size_t base = (size_t)nd * OC + ob * 128 + wq * 64;
    #pragma unroll
    for (int f = 0; f < 4; ++f)
      #pragma unroll
      for (int r = 0; r < 4; ++r) {
        int idx = f * 16 + rowq * 4 + r;
        S1[base + idx] = red[wq * 64 + idx] + q1[f][r];
        S2[base + idx] = red[128 + wq * 64 + idx] + q2[f][r];
      }
  }
}

// ---------------- fused attention + head: per (nd, o) block ----------------
// q -> qw -> dots -> softmax(exact div) -> attn_out ; s in LDS ; WvT GEMV + IN + gelu + Wout.
__global__ __launch_bounds__(256) void attn_fused(
    const float* __restrict__ Wq, const float* __restrict__ Wk,
    const float* __restrict__ xm,
    const _Float16* __restrict__ xpH, const _Float16* __restrict__ xpL,
    const float* __restrict__ WvT, const float* __restrict__ S1,
    const float* __restrict__ S2, const float* __restrict__ gamma,
    const float* __restrict__ beta, const float* __restrict__ Wout,
    const float* __restrict__ bout,
    float* __restrict__ attn_out, float* __restrict__ outs) {
  int bid = blockIdx.x;
  int nd = ((bid >> 5) << 3) | (bid & 7);   // same-nd blocks share XCD
  int o = (bid >> 3) & 3;
  int n = nd >> 5, d = nd & 31;
  int t = threadIdx.x;
  int w = t >> 6, lane = t & 63;
  __shared__ float xs[512];
  __shared__ float qs[8];
  __shared__ float qw[512];
  __shared__ float redm[4];
  __shared__ float reds[4];
  __shared__ float al[196];
  __shared__ float ss[512];
  xs[t] = xm[nd * 512 + t];
  xs[t + 256] = xm[nd * 512 + t + 256];
  __syncthreads();
  // q[kd] = Wq[o*8+kd] . xm
  {
    int kd = t >> 5, j = t & 31;
    const float* wr = Wq + (size_t)(o * 8 + kd) * 512 + j * 16;
    const float* xr = xs + j * 16;
    float p = 0.f;
    #pragma unroll
    for (int i = 0; i < 16; ++i) p = fmaf(wr[i], xr[i], p);
    #pragma unroll
    for (int off = 16; off; off >>= 1) p += __shfl_xor(p, off, 32);
    if (j == 0) qs[kd] = p;
  }
  __syncthreads();
  // qw[c] = sum_kd q[kd] * Wk[o*8+kd][c]
  #pragma unroll
  for (int i = 0; i < 2; ++i) {
    int c = t + i * 256;
    float a = 0.f;
    #pragma unroll
    for (int kd = 0; kd < 8; ++kd)
      a = fmaf(qs[kd], Wk[(size_t)(o * 8 + kd) * 512 + c], a);
    qw[c] = a;
  }
  __syncthreads();
  // dots
  float dval = -3.0e38f;
  if (t < HW) {
    const half8* rh = (const half8*)(xpH + ((size_t)nd * HWP + t) * 512);
    const half8* rl = (const half8*)(xpL + ((size_t)nd * HWP + t) * 512);
    float acc = 0.f;
    for (int cb = 0; cb < 64; ++cb) {
      half8 h = rh[cb], l = rl[cb];
      #pragma unroll
      for (int e = 0; e < 8; ++e)
        acc = fmaf(qw[cb * 8 + e], (float)h[e] + (float)l[e], acc);
    }
    dval = acc * TEMP;
  }
  // softmax (exact division)
  float m = dval;
  #pragma unroll
  for (int off = 32; off; off >>= 1) m = fmaxf(m, __shfl_xor(m, off, 64));
  if (lane == 0) redm[w] = m;
  __syncthreads();
  float bm = fmaxf(fmaxf(redm[0], redm[1]), fmaxf(redm[2], redm[3]));
  float e = (t < HW) ? expf(dval - bm) : 0.f;
  float sum = e;
  #pragma unroll
  for (int off = 32; off; off >>= 1) sum += __shfl_xor(sum, off, 64);
  if (lane == 0) reds[w] = sum;
  __syncthreads();
  float bs = reds[0] + reds[1] + reds[2] + reds[3];
  if (t < HW) {
    float a = e / bs;
    attn_out[(((size_t)n * 4 + o) * 32 + d) * HW + t] = a;
    al[t] = a;
  }
  __syncthreads();
  // s[c] = sum_hw attn[hw] * xp[hw][c]  (c = 2t, 2t+1)
  {
    float a0 = 0.f, a1 = 0.f;
    const _Float16* ph = xpH + (size_t)nd * HWP * 512 + 2 * t;
    const _Float16* pl = xpL + (size_t)nd * HWP * 512 + 2 * t;
    for (int hw = 0; hw < HW; ++hw) {
      half2v h = *(const half2v*)(ph + (size_t)hw * 512);
      half2v l = *(const half2v*)(pl + (size_t)hw * 512);
      float att = al[hw];
      a0 = fmaf(att, (float)h[0] + (float)l[0], a0);
      a1 = fmaf(att, (float)h[1] + (float)l[1], a1);
    }
    ss[2 * t] = a0;
    ss[2 * t + 1] = a1;
  }
  __syncthreads();
  // head: d = WvT . s ; InstanceNorm + gelu + Wout reduce
  float d0 = 0.f, d1 = 0.f;
  #pragma unroll 8
  for (int cp = 0; cp < 512; ++cp) {
    const float* rowp = WvT + (size_t)cp * OC + o * Cc;
    float sv = ss[cp];
    d0 = fmaf(rowp[t], sv, d0);
    d1 = fmaf(rowp[t + 256], sv, d1);
  }
  float partial = 0.f;
  #pragma unroll
  for (int i = 0; i < 2; ++i) {
    int c = t + (i << 8);
    int oc = o * Cc + c;
    float m1 = S1[(size_t)nd * OC + oc] * INV196;
    float m2 = S2[(size_t)nd * OC + oc] * INV196;
    float var = m2 - m1 * m1;
    float rsv = rsqrtf(var + 1e-5f);
    float dv = (i == 0) ? d0 : d1;
    float xh = (dv - m1) * rsv * gamma[oc] + beta[oc];
    float ge = 0.5f * xh * (1.0f + erff(xh * 0.70710678118654752f));
    partial = fmaf(ge, Wout[o * Cc + c], partial);
  }
  #pragma unroll
  for (int off = 32; off; off >>= 1) partial += __shfl_down(partial, off, 64);
  __syncthreads();
  if (lane == 0) redm[w] = partial;
  __syncthreads();
  if (t == 0)
    outs[o * 64 + n * 32 + d] = redm[0] + redm[1] + redm[2] + redm[3] + bout[o];
}

}  // namespace

extern "C" void kernel_launch(void* const* d_in, const int* in_sizes, int n_in,
                              void* d_out, int out_size, void* d_ws, size_t ws_size,
                              hipStream_t stream) {
  const float* x     = (const float*)d_in[0];
  const float* Wq    = (const float*)d_in[1];
  const float* Wk    = (const float*)d_in[2];
  const float* Wv    = (const float*)d_in[3];
  const float* gamma = (const float*)d_in[4];
  const float* beta  = (const float*)d_in[5];
  const float* Wout  = (const float*)d_in[6];
  const float* bout  = (const float*)d_in[7];
  float* out      = (float*)d_out;
  float* attn_out = out;            // (N,4,D,196) = 50176 floats
  float* outs     = out + 50176;    // (4,N,1,D)   = 256 floats

  float* ws = (float*)d_ws;
  float*     WvT = ws;                                  // [0, 1048576)
  _Float16*  WvA = (_Float16*)(ws + 1048576);           // 2097152 f16 -> [1048576, 2097152)
  _Float16*  xpH = (_Float16*)(ws + 2097152);           // 7340032 f16 -> [2097152, 5767168)
  _Float16*  xpL = (_Float16*)(ws + 5767168);           // 7340032 f16 -> [5767168, 9437184)
  float*     xm  = ws + 9437184;                        // 32768
  float*     S1  = ws + 9469952;                        // 131072
  float*     S2  = ws + 9601024;                        // 131072

  wv_prep<<<512, 256, 0, stream>>>(Wv, WvA, WvT);
  pool_kernel<<<4096, 256, 0, stream>>>(x, xpH, xpL, xm);
  moments_mfma<<<1024, 256, 0, stream>>>(WvA, xpH, S1, S2);
  attn_fused<<<256, 256, 0, stream>>>(Wq, Wk, xm, xpH, xpL, WvT, S1, S2,
                                      gamma, beta, Wout, bout, attn_out, outs);
}